// Round 2
// baseline (373.868 us; speedup 1.0000x reference)
//
#include <hip/hip_runtime.h>

#define Tn 200
#define Dn 64
#define Hn 64
#define CC 16   // chunk size for fallback kernel

typedef _Float16 half2v __attribute__((ext_vector_type(2)));
typedef _Float16 half8v __attribute__((ext_vector_type(8)));
typedef float    f32x4  __attribute__((ext_vector_type(4)));

__device__ __forceinline__ float fast_sigmoid(float v) {
    return __builtin_amdgcn_rcpf(1.0f + __expf(-v));
}
__device__ __forceinline__ float fast_tanh(float v) {
    return 1.0f - 2.0f * __builtin_amdgcn_rcpf(1.0f + __expf(2.0f * v));
}
// Intra-wave LDS ordering (wave64 lockstep): drain lgkm queue + compiler fence.
__device__ __forceinline__ void wave_lds_fence() {
    asm volatile("s_waitcnt lgkmcnt(0)" ::: "memory");
}

__device__ __forceinline__ half8v cvt8(const float4 a, const float4 b) {
    return half8v{(_Float16)a.x, (_Float16)a.y, (_Float16)a.z, (_Float16)a.w,
                  (_Float16)b.x, (_Float16)b.y, (_Float16)b.z, (_Float16)b.w};
}

// 4 fdot2 from one half8v into 4 accumulator chains
#define DOT8(v, W, mb, a0, a1, a2, a3)                                  \
    {   const half2v q0 = __builtin_shufflevector(v, v, 0, 1);          \
        const half2v q1 = __builtin_shufflevector(v, v, 2, 3);          \
        const half2v q2 = __builtin_shufflevector(v, v, 4, 5);          \
        const half2v q3 = __builtin_shufflevector(v, v, 6, 7);          \
        a0 = __builtin_amdgcn_fdot2(q0, W[(mb) + 0], a0, false);        \
        a1 = __builtin_amdgcn_fdot2(q1, W[(mb) + 1], a1, false);        \
        a2 = __builtin_amdgcn_fdot2(q2, W[(mb) + 2], a2, false);        \
        a3 = __builtin_amdgcn_fdot2(q3, W[(mb) + 3], a3, false);        }

// ============================================================================
// Kernel 1: x-projection as an MFMA GEMM over flat rows. (unchanged)
// ============================================================================
__global__ __launch_bounds__(256, 4)
void augru_proj_mfma(const float* __restrict__ x,     // [B*T, 64]
                     const int*   __restrict__ slen,  // [B]
                     const float* __restrict__ gk,    // [128][128]
                     const float* __restrict__ gb,    // [128]
                     const float* __restrict__ ck,    // [128][64]
                     const float* __restrict__ cb,    // [64]
                     _Float16*    __restrict__ P,     // [B*T, 192] fp16
                     int nrows, int nchunks)
{
    const int tid  = threadIdx.x;
    const int w    = tid >> 6;      // wave id 0..3
    const int lane = tid & 63;
    const int lm   = lane & 15;     // M (A) / N (B,C) index inside fragment
    const int kq   = lane >> 4;     // K quadrant

    // ---- one-time weight fragment + bias load (registers, persistent) ----
    half8v bf[3][2];
    float  bias[3];
#pragma unroll
    for (int nt = 0; nt < 3; ++nt) {
        const int n = w * 48 + nt * 16 + lm;
#pragma unroll
        for (int kh = 0; kh < 2; ++kh) {
            const int kb = kh * 32 + kq * 8;
            half8v f;
#pragma unroll
            for (int e = 0; e < 8; ++e) {
                const int k = kb + e;
                const float v = (n < 128) ? gk[k * 128 + n]
                                          : ck[k * 64 + (n - 128)];
                f[e] = (_Float16)v;
            }
            bf[nt][kh] = f;
        }
        bias[nt] = (n < 128) ? gb[n] : cb[n - 128];
    }

    for (int chunk = blockIdx.x; chunk < nchunks; chunk += gridDim.x) {
        const int rb0 = chunk * 64;
#pragma unroll
        for (int sub = 0; sub < 4; ++sub) {
            const int rb = rb0 + sub * 16;

            const int rowv = rb + lm;
            const int bv   = rowv / Tn;
            const int tv   = rowv - bv * Tn;
            const bool v   = (rowv < nrows) && (tv < slen[bv]);
            if (__ballot(v) == 0ull) continue;   // whole subtile past seq len

            const int rowA = min(rb + lm, nrows - 1);
            const float* xr = x + (size_t)rowA * Dn + kq * 8;
            const float4 q0 = *(const float4*)(xr);
            const float4 q1 = *(const float4*)(xr + 4);
            const float4 q2 = *(const float4*)(xr + 32);
            const float4 q3 = *(const float4*)(xr + 36);
            const half8v a0 = cvt8(q0, q1);   // k = 0..31 slice
            const half8v a1 = cvt8(q2, q3);   // k = 32..63 slice

            f32x4 acc[3];
#pragma unroll
            for (int nt = 0; nt < 3; ++nt) {
                f32x4 c = {bias[nt], bias[nt], bias[nt], bias[nt]};
                c = __builtin_amdgcn_mfma_f32_16x16x32_f16(a0, bf[nt][0], c, 0, 0, 0);
                c = __builtin_amdgcn_mfma_f32_16x16x32_f16(a1, bf[nt][1], c, 0, 0, 0);
                acc[nt] = c;
            }

#pragma unroll
            for (int r = 0; r < 4; ++r) {
                const int row = rb + kq * 4 + r;
                const int bb  = row / Tn;
                const int tt  = row - bb * Tn;
                if (row < nrows && tt < slen[bb]) {
                    _Float16* Pt = P + (size_t)row * 192 + w * 48 + lm;
                    Pt[0]  = (_Float16)acc[0][r];
                    Pt[16] = (_Float16)acc[1][r];
                    Pt[32] = (_Float16)acc[2][r];
                }
            }
        }
    }
}

// ============================================================================
// Kernel 2 (RESTRUCTURED): recurrence, 1 wave per row.
//  - 2-step-deep P/att register prefetch (named A/B slots, 2x-unrolled loop)
//  - double-buffered s_h/s_rh by t-parity -> trailing WAR fence removed
//  - u-dots moved after the s_rh write (h vectors kept in regs) so the
//    rh LDS round-trip latency is covered by VALU work
// ============================================================================
__device__ __forceinline__ float augru_step(
    float h, int t, int len, int j,
    const _Float16* __restrict__ Prow, const float* __restrict__ arow,
    float* __restrict__ orow,
    _Float16& pr_s, _Float16& pu_s, _Float16& pc_s, float& a_s,
    const half2v* __restrict__ wr, const half2v* __restrict__ wu,
    const half2v* __restrict__ wc,
    _Float16* __restrict__ sh, _Float16* __restrict__ srh)
{
    // consume values prefetched 2 steps ago
    const float pr = (float)pr_s;
    const float pu = (float)pu_s;
    const float pc = (float)pc_s;
    const float a  = a_s;

    // issue prefetch for t+2 (clamped) into the same named slot
    const int tn = min(t + 2, len - 1);
    const _Float16* Pt = Prow + (size_t)tn * 192;
    pr_s = Pt[j]; pu_s = Pt[64 + j]; pc_s = Pt[128 + j];
    a_s  = arow[tn];

    // ---- broadcast h through LDS buffer for this parity ----
    sh[j] = (_Float16)h;
    wave_lds_fence();

    const half8v* hv = (const half8v*)sh;
    const half8v v0 = hv[0], v1 = hv[1], v2 = hv[2], v3 = hv[3];
    const half8v v4 = hv[4], v5 = hv[5], v6 = hv[6], v7 = hv[7];

    // ---- r gate (4 chains) ----
    float r0 = pr, r1 = 0.f, r2 = 0.f, r3 = 0.f;
    DOT8(v0, wr,  0, r0, r1, r2, r3);
    DOT8(v1, wr,  4, r0, r1, r2, r3);
    DOT8(v2, wr,  8, r0, r1, r2, r3);
    DOT8(v3, wr, 12, r0, r1, r2, r3);
    DOT8(v4, wr, 16, r0, r1, r2, r3);
    DOT8(v5, wr, 20, r0, r1, r2, r3);
    DOT8(v6, wr, 24, r0, r1, r2, r3);
    DOT8(v7, wr, 28, r0, r1, r2, r3);
    const float rg = fast_sigmoid((r0 + r1) + (r2 + r3));

    // write r*h early; u-dots below execute under the LDS round-trip
    srh[j] = (_Float16)(rg * h);

    // ---- u gate from the register copies of h ----
    float u0 = pu, u1 = 0.f, u2 = 0.f, u3 = 0.f;
    DOT8(v0, wu,  0, u0, u1, u2, u3);
    DOT8(v1, wu,  4, u0, u1, u2, u3);
    DOT8(v2, wu,  8, u0, u1, u2, u3);
    DOT8(v3, wu, 12, u0, u1, u2, u3);
    DOT8(v4, wu, 16, u0, u1, u2, u3);
    DOT8(v5, wu, 20, u0, u1, u2, u3);
    DOT8(v6, wu, 24, u0, u1, u2, u3);
    DOT8(v7, wu, 28, u0, u1, u2, u3);
    const float ug = fast_sigmoid((u0 + u1) + (u2 + u3));

    wave_lds_fence();

    // ---- candidate ----
    const half8v* rv = (const half8v*)srh;
    float c0 = pc, c1 = 0.f, c2 = 0.f, c3 = 0.f;
    {
        const half8v w0 = rv[0], w1 = rv[1], w2 = rv[2], w3 = rv[3];
        const half8v w4 = rv[4], w5 = rv[5], w6 = rv[6], w7 = rv[7];
        DOT8(w0, wc,  0, c0, c1, c2, c3);
        DOT8(w1, wc,  4, c0, c1, c2, c3);
        DOT8(w2, wc,  8, c0, c1, c2, c3);
        DOT8(w3, wc, 12, c0, c1, c2, c3);
        DOT8(w4, wc, 16, c0, c1, c2, c3);
        DOT8(w5, wc, 20, c0, c1, c2, c3);
        DOT8(w6, wc, 24, c0, c1, c2, c3);
        DOT8(w7, wc, 28, c0, c1, c2, c3);
    }
    const float cg = fast_tanh((c0 + c1) + (c2 + c3));

    const float uh = (1.0f - a) * ug;
    h = uh * h + (1.0f - uh) * cg;
    orow[(size_t)t * Hn + j] = h;
    // no trailing fence: buffers are parity-alternated; this step's own
    // fences drain all reads long before t+2 rewrites this buffer.
    return h;
}

__global__ __launch_bounds__(64, 2)
void augru_rec(const _Float16* __restrict__ P,   // [B,T,3,64] fp16
               const int*     __restrict__ slen, // [B]
               const float*   __restrict__ att,  // [B,T]
               const float*   __restrict__ gk,   // [128][128]
               const float*   __restrict__ ck,   // [128][64]
               float*         __restrict__ out)  // [B,T,H]
{
    const int b = blockIdx.x;
    const int j = threadIdx.x;

    __shared__ __align__(16) _Float16 s_h0[Hn];
    __shared__ __align__(16) _Float16 s_rh0[Hn];
    __shared__ __align__(16) _Float16 s_h1[Hn];
    __shared__ __align__(16) _Float16 s_rh1[Hn];

    half2v wr[32], wu[32], wc[32];   // h-part weight cols (K rows 64..127)
#pragma unroll
    for (int m = 0; m < 32; ++m) {
        const int k = 64 + 2 * m;
        wr[m] = half2v{(_Float16)gk[(k + 0) * 128 + j],
                       (_Float16)gk[(k + 1) * 128 + j]};
        wu[m] = half2v{(_Float16)gk[(k + 0) * 128 + 64 + j],
                       (_Float16)gk[(k + 1) * 128 + 64 + j]};
        wc[m] = half2v{(_Float16)ck[(k + 0) * 64 + j],
                       (_Float16)ck[(k + 1) * 64 + j]};
    }

    const int len = slen[b];
    const _Float16* Prow = P   + (size_t)b * Tn * 192;
    const float*    arow = att + (size_t)b * Tn;
    float*          orow = out + (size_t)b * Tn * Hn;

    float h = 0.0f;

    if (len > 0) {
        // prologue: fill both prefetch slots (t=0 -> A, t=1 clamped -> B)
        _Float16 prA = Prow[j], puA = Prow[64 + j], pcA = Prow[128 + j];
        float    aA  = arow[0];
        const int t1 = min(1, len - 1);
        const _Float16* P1 = Prow + (size_t)t1 * 192;
        _Float16 prB = P1[j], puB = P1[64 + j], pcB = P1[128 + j];
        float    aB  = arow[t1];

        int t = 0;
        while (true) {
            h = augru_step(h, t, len, j, Prow, arow, orow,
                           prA, puA, pcA, aA, wr, wu, wc, s_h0, s_rh0);
            ++t; if (t >= len) break;
            h = augru_step(h, t, len, j, Prow, arow, orow,
                           prB, puB, pcB, aB, wr, wu, wc, s_h1, s_rh1);
            ++t; if (t >= len) break;
        }
    }

    // ---- zero tail: out[b, len:T, :] = 0 ----
    float4 z;
    z.x = z.y = z.z = z.w = 0.0f;
    float* tail = orow + (size_t)len * Hn;
    const int total = (Tn - len) * Hn;
    for (int i = j * 4; i < total; i += 64 * 4) {
        *(float4*)(tail + i) = z;
    }
}

// ============================================================================
// Fallback (R4 fused, 430 us) if ws is too small for P. (unchanged)
// ============================================================================
__global__ __launch_bounds__(128, 2)
void augru_fused_fb(const float* __restrict__ x, const int* __restrict__ slen,
                    const float* __restrict__ att, const float* __restrict__ gk,
                    const float* __restrict__ gb, const float* __restrict__ ck,
                    const float* __restrict__ cb, float* __restrict__ out)
{
    const int b    = blockIdx.x;
    const int tid  = threadIdx.x;
    const int wave = tid >> 6;
    const int j    = tid & 63;

    __shared__ float s_P[2][CC][3][Hn];
    __shared__ __align__(16) _Float16 s_h[Hn];
    __shared__ __align__(16) _Float16 s_rh[Hn];

    const int len     = slen[b];
    const int nchunks = (len + CC - 1) / CC;
    const float* xrow = x   + (size_t)b * Tn * Dn;
    const float* arow = att + (size_t)b * Tn;
    float*       orow = out + (size_t)b * Tn * Hn;

    if (wave == 0) {
        half2v wr[32], wu[32], wc[32];
#pragma unroll
        for (int m = 0; m < 32; ++m) {
            const int k = 2 * m;
            wr[m] = half2v{(_Float16)gk[(k + 0) * 128 + j], (_Float16)gk[(k + 1) * 128 + j]};
            wu[m] = half2v{(_Float16)gk[(k + 0) * 128 + 64 + j], (_Float16)gk[(k + 1) * 128 + 64 + j]};
            wc[m] = half2v{(_Float16)ck[(k + 0) * 64 + j], (_Float16)ck[(k + 1) * 64 + j]};
        }
        const float br = gb[j], bu = gb[64 + j], bc = cb[j];
        for (int c = 0; c < nchunks; ++c) {
            const int t0 = c * CC, tend = min(len, t0 + CC);
            for (int t = t0; t < tend; ++t) {
                const float4* xv = (const float4*)(xrow + t * Dn);
                float r0 = br, r1 = 0.f, u0 = bu, u1 = 0.f, c0 = bc, c1 = 0.f;
#pragma unroll
                for (int kk = 0; kk < 16; ++kk) {
                    const float4 q = xv[kk];
                    const half2v p0 = half2v{(_Float16)q.x, (_Float16)q.y};
                    const half2v p1 = half2v{(_Float16)q.z, (_Float16)q.w};
                    const int m = 2 * kk;
                    r0 = __builtin_amdgcn_fdot2(p0, wr[m], r0, false);
                    r1 = __builtin_amdgcn_fdot2(p1, wr[m + 1], r1, false);
                    u0 = __builtin_amdgcn_fdot2(p0, wu[m], u0, false);
                    u1 = __builtin_amdgcn_fdot2(p1, wu[m + 1], u1, false);
                    c0 = __builtin_amdgcn_fdot2(p0, wc[m], c0, false);
                    c1 = __builtin_amdgcn_fdot2(p1, wc[m + 1], c1, false);
                }
                const int lt = t - t0;
                s_P[c & 1][lt][0][j] = r0 + r1;
                s_P[c & 1][lt][1][j] = u0 + u1;
                s_P[c & 1][lt][2][j] = c0 + c1;
            }
            __syncthreads();
        }
    } else {
        half2v wr[32], wu[32], wc[32];
#pragma unroll
        for (int m = 0; m < 32; ++m) {
            const int k = 64 + 2 * m;
            wr[m] = half2v{(_Float16)gk[(k + 0) * 128 + j], (_Float16)gk[(k + 1) * 128 + j]};
            wu[m] = half2v{(_Float16)gk[(k + 0) * 128 + 64 + j], (_Float16)gk[(k + 1) * 128 + 64 + j]};
            wc[m] = half2v{(_Float16)ck[(k + 0) * 64 + j], (_Float16)ck[(k + 1) * 64 + j]};
        }
        float h = 0.0f;
        for (int c = 0; c < nchunks; ++c) {
            __syncthreads();
            const int t0 = c * CC, tend = min(len, t0 + CC);
            for (int t = t0; t < tend; ++t) {
                const int lt = t - t0;
                const float pr = s_P[c & 1][lt][0][j];
                const float pu = s_P[c & 1][lt][1][j];
                const float pc = s_P[c & 1][lt][2][j];
                const float a  = arow[t];
                s_h[j] = (_Float16)h;
                wave_lds_fence();
                float r0 = pr, r1 = 0.f, u0 = pu, u1 = 0.f;
                const half8v* hv = (const half8v*)s_h;
#pragma unroll
                for (int m8 = 0; m8 < 8; ++m8) {
                    const half8v v = hv[m8];
                    const half2v p0 = __builtin_shufflevector(v, v, 0, 1);
                    const half2v p1 = __builtin_shufflevector(v, v, 2, 3);
                    const half2v p2 = __builtin_shufflevector(v, v, 4, 5);
                    const half2v p3 = __builtin_shufflevector(v, v, 6, 7);
                    const int m = m8 * 4;
                    r0 = __builtin_amdgcn_fdot2(p0, wr[m + 0], r0, false);
                    r1 = __builtin_amdgcn_fdot2(p1, wr[m + 1], r1, false);
                    r0 = __builtin_amdgcn_fdot2(p2, wr[m + 2], r0, false);
                    r1 = __builtin_amdgcn_fdot2(p3, wr[m + 3], r1, false);
                    u0 = __builtin_amdgcn_fdot2(p0, wu[m + 0], u0, false);
                    u1 = __builtin_amdgcn_fdot2(p1, wu[m + 1], u1, false);
                    u0 = __builtin_amdgcn_fdot2(p2, wu[m + 2], u0, false);
                    u1 = __builtin_amdgcn_fdot2(p3, wu[m + 3], u1, false);
                }
                const float rg = fast_sigmoid(r0 + r1);
                const float ug = fast_sigmoid(u0 + u1);
                s_rh[j] = (_Float16)(rg * h);
                wave_lds_fence();
                float c0 = pc, c1 = 0.f;
                const half8v* rv = (const half8v*)s_rh;
#pragma unroll
                for (int m8 = 0; m8 < 8; ++m8) {
                    const half8v v = rv[m8];
                    const half2v p0 = __builtin_shufflevector(v, v, 0, 1);
                    const half2v p1 = __builtin_shufflevector(v, v, 2, 3);
                    const half2v p2 = __builtin_shufflevector(v, v, 4, 5);
                    const half2v p3 = __builtin_shufflevector(v, v, 6, 7);
                    const int m = m8 * 4;
                    c0 = __builtin_amdgcn_fdot2(p0, wc[m + 0], c0, false);
                    c1 = __builtin_amdgcn_fdot2(p1, wc[m + 1], c1, false);
                    c0 = __builtin_amdgcn_fdot2(p2, wc[m + 2], c0, false);
                    c1 = __builtin_amdgcn_fdot2(p3, wc[m + 3], c1, false);
                }
                const float cg = fast_tanh(c0 + c1);
                const float uh = (1.0f - a) * ug;
                h = uh * h + (1.0f - uh) * cg;
                orow[t * Hn + j] = h;
                wave_lds_fence();
            }
        }
    }
    float4 z; z.x = z.y = z.z = z.w = 0.0f;
    float* tail = orow + len * Hn;
    const int total = (Tn - len) * Hn;
    for (int i = tid * 4; i < total; i += 128 * 4) *(float4*)(tail + i) = z;
}

extern "C" void kernel_launch(void* const* d_in, const int* in_sizes, int n_in,
                              void* d_out, int out_size, void* d_ws, size_t ws_size,
                              hipStream_t stream) {
    const float* x    = (const float*)d_in[0];
    const int*   slen = (const int*)  d_in[1];
    const float* att  = (const float*)d_in[2];
    const float* gk   = (const float*)d_in[3];
    const float* gb   = (const float*)d_in[4];
    const float* ck   = (const float*)d_in[5];
    const float* cb   = (const float*)d_in[6];
    float* out = (float*)d_out;

    const int B = in_sizes[1];  // 2048
    const size_t needP = (size_t)B * Tn * 192 * sizeof(_Float16);  // 157 MB

    if (ws_size >= needP) {
        _Float16* P = (_Float16*)d_ws;
        const int nrows   = B * Tn;
        const int nchunks = (nrows + 63) / 64;
        const int grid    = nchunks < 1024 ? nchunks : 1024;
        augru_proj_mfma<<<grid, 256, 0, stream>>>(x, slen, gk, gb, ck, cb, P,
                                                  nrows, nchunks);
        augru_rec<<<B, 64, 0, stream>>>(P, slen, att, gk, ck, out);
    } else {
        augru_fused_fb<<<B, 128, 0, stream>>>(x, slen, att, gk, gb, ck, cb, out);
    }
}